// Round 1
// baseline (257.714 us; speedup 1.0000x reference)
//
#include <hip/hip_runtime.h>
#include <hip/hip_bf16.h>
#include <stdint.h>

using bf16 = __hip_bfloat16;
typedef __attribute__((ext_vector_type(8))) short short8;
typedef __attribute__((ext_vector_type(4))) float floatx4;

#define DD 32
#define DL3 32768      // 32^3
#define BATCH 256
#define NK 1024        // 32*32

// async global->LDS, 16B per lane (wave-uniform base + lane*16 layout respected)
__device__ __forceinline__ void load16(const void* g, void* l) {
  __builtin_amdgcn_global_load_lds((const __attribute__((address_space(1))) void*)g,
                                   (__attribute__((address_space(3))) void*)l,
                                   16, 0, 0);
}

// dst[b][v][f][u] = x[b][u][v][f]  (fp32 -> bf16), so GEMM step 0 uses the same
// A-gather pattern as steps 1..5:  A[(b,f)][(v*32+u)] = src[b,v,f,u]
__global__ void prep_x(const float* __restrict__ x, bf16* __restrict__ dst) {
  int b = blockIdx.x >> 5, v = blockIdx.x & 31;
  __shared__ float tile[32][33];
  const float* xb = x + (size_t)b * DL3 + v * DD;
  int t = threadIdx.x;
#pragma unroll
  for (int it = 0; it < 4; ++it) {
    int u = (t >> 5) + it * 8, f = t & 31;
    tile[u][f] = xb[u * NK + f];               // coalesced 128B per 32 lanes
  }
  __syncthreads();
  bf16* db = dst + (size_t)b * DL3 + v * NK;
#pragma unroll
  for (int it = 0; it < 4; ++it) {
    int f = (t >> 5) + it * 8, u = t & 31;
    db[f * DD + u] = __float2bfloat16(tile[u][f]);  // contiguous bf16 writes
  }
}

// nodeT[i][n][v*32+u] = node[i][u*32+v][n]  (fp32 -> bf16)
// (u,v swap makes A's k-dimension memory-contiguous; transpose makes B-frag reads b128)
__global__ void prep_nodes(const float* __restrict__ nodes, bf16* __restrict__ dst) {
  int id = blockIdx.x;
  int nb = id & 31, kb = (id >> 5) & 31, i = id >> 10;
  const float* src = nodes + (size_t)i * 1048576;
  bf16* d = dst + (size_t)i * 1048576;
  __shared__ float tile[32][33];
  int t = threadIdx.x;
#pragma unroll
  for (int it = 0; it < 4; ++it) {
    int u = (t >> 5) + it * 8, j = t & 31;
    tile[u][j] = src[(size_t)(u * 32 + kb) * 1024 + nb * 32 + j];
  }
  __syncthreads();
#pragma unroll
  for (int it = 0; it < 4; ++it) {
    int j = (t >> 5) + it * 8, u = t & 31;
    d[(size_t)(nb * 32 + j) * 1024 + kb * 32 + u] = __float2bfloat16(tile[u][j]);
  }
}

// One contraction step as GEMM: C[(b*32+f)][n] = sum_k A[(b,f)][k] * Bt[k][n]
//   A[(b,f)][(v*32+u)] = Asrc[b*32768 + v*1024 + f*32 + u]   (k-contiguous runs of 32)
//   Bt[k][n] = nodeT[n][k]
// Tile 128x128, BK=32, 4 waves each owning a 64x64 quadrant (16 MFMA / 8 ds_read_b128 per k-step).
template <bool FINAL>
__global__ __launch_bounds__(256) void entangler_gemm(
    const bf16* __restrict__ A, const bf16* __restrict__ Bn,
    bf16* __restrict__ Cb, float* __restrict__ Cf, const float* __restrict__ bias) {
  __shared__ bf16 sA[128 * 32];   // [m][k] : m=(b-b0)*32+f, k=u
  __shared__ bf16 sB[128 * 32];   // [n][k]
  const int t = threadIdx.x;
  const int lane = t & 63;
  const int lane16 = lane & 15, quad = lane >> 4;
  const int w = t >> 6;
  const int m0 = (w >> 1) * 64, n0 = (w & 1) * 64;
  const int b0 = blockIdx.x * 4;          // 4 batch elements per M-tile of 128
  const int N0 = blockIdx.y * 128;

  floatx4 acc[4][4];
#pragma unroll
  for (int i = 0; i < 4; ++i)
#pragma unroll
    for (int j = 0; j < 4; ++j)
      acc[i][j] = (floatx4){0.f, 0.f, 0.f, 0.f};

  const bf16* Ab = A + (size_t)b0 * DL3;
  const bf16* Bb = Bn + (size_t)N0 * NK;

  for (int kv = 0; kv < 32; ++kv) {
    __syncthreads();   // protect LDS from previous iteration's readers
#pragma unroll
    for (int r = 0; r < 2; ++r) {
      int idx = r * 256 + t;
      // A: element idx*8 of sA <- contiguous 2KB chunk per (b,v); fully coalesced
      load16(Ab + (size_t)(idx >> 7) * DL3 + kv * NK + (idx & 127) * 8, sA + idx * 8);
      // B: row n = idx>>2 of nodeT, 64B run per 4 lanes
      load16(Bb + (size_t)(idx >> 2) * NK + kv * 32 + (idx & 3) * 8, sB + idx * 8);
    }
    __syncthreads();   // compiler drains vmcnt here

    short8 af[4], bfr[4];
#pragma unroll
    for (int i = 0; i < 4; ++i)
      af[i] = *(const short8*)(sA + (m0 + i * 16 + lane16) * 32 + quad * 8);
#pragma unroll
    for (int j = 0; j < 4; ++j)
      bfr[j] = *(const short8*)(sB + (n0 + j * 16 + lane16) * 32 + quad * 8);
#pragma unroll
    for (int i = 0; i < 4; ++i)
#pragma unroll
      for (int j = 0; j < 4; ++j)
        acc[i][j] = __builtin_amdgcn_mfma_f32_16x16x32_bf16(af[i], bfr[j], acc[i][j], 0, 0, 0);
  }

  // Epilogue. C/D layout: col = lane&15, row = quad*4 + reg  [m89-verified]
  const int R0 = blockIdx.x * 128;
#pragma unroll
  for (int i = 0; i < 4; ++i) {
#pragma unroll
    for (int j = 0; j < 4; ++j) {
#pragma unroll
      for (int r = 0; r < 4; ++r) {
        int row = R0 + m0 + i * 16 + quad * 4 + r;
        int col = N0 + n0 + j * 16 + lane16;
        if (FINAL) {
          float v = acc[i][j][r] + bias[(row & 31) * 1024 + col];
          Cf[(size_t)row * 1024 + col] = fmaxf(v, 0.f);
        } else {
          Cb[(size_t)row * 1024 + col] = __float2bfloat16(acc[i][j][r]);
        }
      }
    }
  }
}

extern "C" void kernel_launch(void* const* d_in, const int* in_sizes, int n_in,
                              void* d_out, int out_size, void* d_ws, size_t ws_size,
                              hipStream_t stream) {
  const float* x     = (const float*)d_in[0];   // (256, 32768) fp32
  const float* nodes = (const float*)d_in[1];   // (6, 32,32,32,32) fp32
  const float* bias  = (const float*)d_in[2];   // (32768,) fp32
  float* out = (float*)d_out;                   // (256, 32768) fp32

  // ws layout: buf0 16MB | buf1 16MB | nodeT 12MB  => 44MB needed
  bf16* buf0  = (bf16*)d_ws;
  bf16* buf1  = buf0 + (size_t)BATCH * DL3;
  bf16* nodeT = buf1 + (size_t)BATCH * DL3;

  prep_x<<<dim3(BATCH * 32), dim3(256), 0, stream>>>(x, buf0);
  prep_nodes<<<dim3(6 * 1024), dim3(256), 0, stream>>>(nodes, nodeT);

  dim3 grid(64, 8), blk(256);
  entangler_gemm<false><<<grid, blk, 0, stream>>>(buf0, nodeT + (size_t)0 * 1048576, buf1, nullptr, nullptr);
  entangler_gemm<false><<<grid, blk, 0, stream>>>(buf1, nodeT + (size_t)1 * 1048576, buf0, nullptr, nullptr);
  entangler_gemm<false><<<grid, blk, 0, stream>>>(buf0, nodeT + (size_t)2 * 1048576, buf1, nullptr, nullptr);
  entangler_gemm<false><<<grid, blk, 0, stream>>>(buf1, nodeT + (size_t)3 * 1048576, buf0, nullptr, nullptr);
  entangler_gemm<false><<<grid, blk, 0, stream>>>(buf0, nodeT + (size_t)4 * 1048576, buf1, nullptr, nullptr);
  entangler_gemm<true ><<<grid, blk, 0, stream>>>(buf1, nodeT + (size_t)5 * 1048576, nullptr, out, bias);
}

// Round 2
// 233.335 us; speedup vs baseline: 1.1045x; 1.1045x over previous
//
#include <hip/hip_runtime.h>
#include <hip/hip_bf16.h>
#include <stdint.h>

using bf16 = __hip_bfloat16;
typedef __attribute__((ext_vector_type(8))) short short8;
typedef __attribute__((ext_vector_type(4))) float floatx4;

#define DD 32
#define DL3 32768      // 32^3
#define BATCH 256
#define NK 1024        // 32*32

// async global->LDS, 16B per lane (wave-uniform base + lane*16 layout respected)
__device__ __forceinline__ void load16(const void* g, void* l) {
  __builtin_amdgcn_global_load_lds((const __attribute__((address_space(1))) void*)g,
                                   (__attribute__((address_space(3))) void*)l,
                                   16, 0, 0);
}

// dst[b][v][f][u] = x[b][u][v][f]  (fp32 -> bf16), so GEMM step 0 uses the same
// A-gather pattern as steps 1..5:  A[(b,f)][(v*32+u)] = src[b,v,f,u]
__global__ __launch_bounds__(256) void prep_x(const float* __restrict__ x, bf16* __restrict__ dst) {
  int b = blockIdx.x >> 5, v = blockIdx.x & 31;
  __shared__ float tile[32][33];
  const float* xb = x + (size_t)b * DL3 + v * DD;
  int t = threadIdx.x;
#pragma unroll
  for (int it = 0; it < 4; ++it) {
    int u = (t >> 5) + it * 8, f = t & 31;
    tile[u][f] = xb[u * NK + f];               // coalesced 128B per 32 lanes
  }
  __syncthreads();
  bf16* db = dst + (size_t)b * DL3 + v * NK;
#pragma unroll
  for (int it = 0; it < 4; ++it) {
    int f = (t >> 5) + it * 8, u = t & 31;
    db[f * DD + u] = __float2bfloat16(tile[u][f]);  // contiguous bf16 writes
  }
}

// nodeT[i][n][v*32+u] = node[i][u*32+v][n]  (fp32 -> bf16)
__global__ __launch_bounds__(256) void prep_nodes(const float* __restrict__ nodes, bf16* __restrict__ dst) {
  int id = blockIdx.x;
  int nb = id & 31, kb = (id >> 5) & 31, i = id >> 10;
  const float* src = nodes + (size_t)i * 1048576;
  bf16* d = dst + (size_t)i * 1048576;
  __shared__ float tile[32][33];
  int t = threadIdx.x;
#pragma unroll
  for (int it = 0; it < 4; ++it) {
    int u = (t >> 5) + it * 8, j = t & 31;
    tile[u][j] = src[(size_t)(u * 32 + kb) * 1024 + nb * 32 + j];
  }
  __syncthreads();
#pragma unroll
  for (int it = 0; it < 4; ++it) {
    int j = (t >> 5) + it * 8, u = t & 31;
    d[(size_t)(nb * 32 + j) * 1024 + kb * 32 + u] = __float2bfloat16(tile[u][j]);
  }
}

// One contraction step as GEMM: C[(b*32+f)][n] = sum_k A[(b,f)][k] * Bt[k][n]
//   A[(b,f)][(v*32+u)] = Asrc[b*32768 + v*1024 + f*32 + u]   (k-contiguous runs of 32)
//   Bt[k][n] = nodeT[n][k]
// Tile 128x128, BK=128 (4 v-chunks per barrier pair; 64 MFMA/wave between barriers).
// LDS = 2 x 32KB = 64KB -> 2 blocks/CU (grid is 512 = 2/CU anyway).
template <bool FINAL>
__global__ __launch_bounds__(256) void entangler_gemm(
    const bf16* __restrict__ A, const bf16* __restrict__ Bn,
    bf16* __restrict__ Cb, float* __restrict__ Cf, const float* __restrict__ bias) {
  __shared__ bf16 sA[4 * 128 * 32];   // [vv][m][u] : m=(b-b0)*32+f
  __shared__ bf16 sB[4 * 128 * 32];   // [vv][n][u]
  const int t = threadIdx.x;
  const int lane = t & 63;
  const int lane16 = lane & 15, quad = lane >> 4;
  const int w = t >> 6;
  const int m0 = (w >> 1) * 64, n0 = (w & 1) * 64;
  const int b0 = blockIdx.x * 4;          // 4 batch elements per M-tile of 128
  const int N0 = blockIdx.y * 128;

  floatx4 acc[4][4];
#pragma unroll
  for (int i = 0; i < 4; ++i)
#pragma unroll
    for (int j = 0; j < 4; ++j)
      acc[i][j] = (floatx4){0.f, 0.f, 0.f, 0.f};

  const bf16* Ab = A + (size_t)b0 * DL3;
  const bf16* Bb = Bn + (size_t)N0 * NK;

  for (int kv = 0; kv < 8; ++kv) {        // 8 iters of BK=128 (4 v-chunks each)
    __syncthreads();   // protect LDS from previous iteration's readers
#pragma unroll
    for (int r = 0; r < 8; ++r) {
      int e = (r * 256 + t) * 8;          // flat bf16 element index into sA/sB
      int vv = e >> 12;                   // 0..3  sub-chunk
      // A: lds flat [vv][bb*32+f][u] matches global [vv][bb][f][u] per-chunk
      int bb = (e >> 10) & 3;
      int remA = e & 1023;                // f*32+u
      load16(Ab + (size_t)bb * DL3 + (kv * 4 + vv) * NK + remA, sA + e);
      // B: lds flat [vv][n][u]
      int n = (e >> 5) & 127;
      int u8 = e & 31;
      load16(Bb + (size_t)n * NK + (kv * 4 + vv) * 32 + u8, sB + e);
    }
    __syncthreads();   // vmcnt drain here (once per 128 k)

#pragma unroll
    for (int kk = 0; kk < 4; ++kk) {
      const bf16* pA = sA + kk * 4096;
      const bf16* pB = sB + kk * 4096;
      short8 af[4], bfr[4];
#pragma unroll
      for (int i = 0; i < 4; ++i)
        af[i] = *(const short8*)(pA + (m0 + i * 16 + lane16) * 32 + quad * 8);
#pragma unroll
      for (int j = 0; j < 4; ++j)
        bfr[j] = *(const short8*)(pB + (n0 + j * 16 + lane16) * 32 + quad * 8);
#pragma unroll
      for (int i = 0; i < 4; ++i)
#pragma unroll
        for (int j = 0; j < 4; ++j)
          acc[i][j] = __builtin_amdgcn_mfma_f32_16x16x32_bf16(af[i], bfr[j], acc[i][j], 0, 0, 0);
    }
  }

  // Epilogue. C/D layout: col = lane&15, row = quad*4 + reg  [m89-verified]
  const int R0 = blockIdx.x * 128;
#pragma unroll
  for (int i = 0; i < 4; ++i) {
#pragma unroll
    for (int j = 0; j < 4; ++j) {
#pragma unroll
      for (int r = 0; r < 4; ++r) {
        int row = R0 + m0 + i * 16 + quad * 4 + r;
        int col = N0 + n0 + j * 16 + lane16;
        if (FINAL) {
          float v = acc[i][j][r] + bias[(row & 31) * 1024 + col];
          Cf[(size_t)row * 1024 + col] = fmaxf(v, 0.f);
        } else {
          Cb[(size_t)row * 1024 + col] = __float2bfloat16(acc[i][j][r]);
        }
      }
    }
  }
}

extern "C" void kernel_launch(void* const* d_in, const int* in_sizes, int n_in,
                              void* d_out, int out_size, void* d_ws, size_t ws_size,
                              hipStream_t stream) {
  const float* x     = (const float*)d_in[0];   // (256, 32768) fp32
  const float* nodes = (const float*)d_in[1];   // (6, 32,32,32,32) fp32
  const float* bias  = (const float*)d_in[2];   // (32768,) fp32
  float* out = (float*)d_out;                   // (256, 32768) fp32

  // ws layout: buf0 16MB | buf1 16MB | nodeT 12MB  => 44MB needed
  bf16* buf0  = (bf16*)d_ws;
  bf16* buf1  = buf0 + (size_t)BATCH * DL3;
  bf16* nodeT = buf1 + (size_t)BATCH * DL3;

  prep_x<<<dim3(BATCH * 32), dim3(256), 0, stream>>>(x, buf0);
  prep_nodes<<<dim3(6 * 1024), dim3(256), 0, stream>>>(nodes, nodeT);

  dim3 grid(64, 8), blk(256);
  entangler_gemm<false><<<grid, blk, 0, stream>>>(buf0, nodeT + (size_t)0 * 1048576, buf1, nullptr, nullptr);
  entangler_gemm<false><<<grid, blk, 0, stream>>>(buf1, nodeT + (size_t)1 * 1048576, buf0, nullptr, nullptr);
  entangler_gemm<false><<<grid, blk, 0, stream>>>(buf0, nodeT + (size_t)2 * 1048576, buf1, nullptr, nullptr);
  entangler_gemm<false><<<grid, blk, 0, stream>>>(buf1, nodeT + (size_t)3 * 1048576, buf0, nullptr, nullptr);
  entangler_gemm<false><<<grid, blk, 0, stream>>>(buf0, nodeT + (size_t)4 * 1048576, buf1, nullptr, nullptr);
  entangler_gemm<true ><<<grid, blk, 0, stream>>>(buf1, nodeT + (size_t)5 * 1048576, nullptr, out, bias);
}